// Round 4
// baseline (712.488 us; speedup 1.0000x reference)
//
#include <hip/hip_runtime.h>
#include <stdint.h>

typedef __attribute__((ext_vector_type(4))) float f32x4;
typedef __attribute__((ext_vector_type(8))) short s16x8;

#define MFMA16(A, B, C) __builtin_amdgcn_mfma_f32_16x16x32_bf16(A, B, C, 0, 0, 0)
#define WAIT_VM(N) asm volatile("s_waitcnt vmcnt(" #N ")" ::: "memory")
#define WAIT_LGKM() asm volatile("s_waitcnt lgkmcnt(0)" ::: "memory")
#define BAR() __builtin_amdgcn_s_barrier()

__device__ __forceinline__ unsigned short f2bf(float x) {
  union { float f; unsigned u; } v; v.f = x;
  return (unsigned short)((v.u + 0x7fffu + ((v.u >> 16) & 1u)) >> 16);
}

// ---------------- cast f32 -> bf16, 4 elems/thread ----------------
__global__ void k_cast_bf16(const float* __restrict__ in, unsigned short* __restrict__ out, int n4) {
  int i = blockIdx.x * blockDim.x + threadIdx.x;
  const int stride = gridDim.x * blockDim.x;
  for (; i < n4; i += stride) {
    const float4 v = ((const float4*)in)[i];
    ushort4 o;
    o.x = f2bf(v.x); o.y = f2bf(v.y); o.z = f2bf(v.z); o.w = f2bf(v.w);
    ((ushort4*)out)[i] = o;
  }
}

// ---------------- exc [16384][28] -> excT bf16 [32][16384] (rows 28..31 = 0) + b[28] ----------------
__global__ void k_excT(const float* __restrict__ exc, unsigned short* __restrict__ excT,
                       float* __restrict__ bvec) {
  const int c = blockIdx.x;        // 0..31
  const int tid = threadIdx.x;     // 256
  float sum = 0.f;
  for (int j = tid; j < 16384; j += 256) {
    const float v = (c < 28) ? exc[(size_t)j * 28 + c] : 0.f;
    excT[(size_t)c * 16384 + j] = f2bf(v);
    sum += v;
  }
  #pragma unroll
  for (int o = 32; o; o >>= 1) sum += __shfl_down(sum, o, 64);
  __shared__ float wsum[4];
  if ((tid & 63) == 0) wsum[tid >> 6] = sum;
  __syncthreads();
  if (tid == 0 && c < 28) bvec[c] = fmaxf(wsum[0] + wsum[1] + wsum[2] + wsum[3], 1.0f);
}

// ---- stage one 256x32 bf16 tile (row-major, leading-dim ld) into LDS at dsoff (shorts) ----
// 512 threads, 2 global_load_lds each (rows 0..127 then 128..255).
// LDS[row][cb] = G[row][cb ^ ((row>>1)&3)]; dest is linear (base + lane*16B).
// offsrc = rowL*ld + ((lane&3)^((rowL>>1)&3))*8 precomputed; row+128 has same swizzle.
#define STAGE(SRC, LD, DSOFF)                                                                 \
  do {                                                                                        \
    __builtin_amdgcn_global_load_lds(                                                         \
        (const __attribute__((address_space(1))) unsigned int*)((SRC) + offsrc),              \
        (__attribute__((address_space(3))) unsigned int*)(smem + (DSOFF) + w * 512), 16, 0, 0);\
    __builtin_amdgcn_global_load_lds(                                                         \
        (const __attribute__((address_space(1))) unsigned int*)((SRC) + offsrc + 128 * (LD)), \
        (__attribute__((address_space(3))) unsigned int*)(smem + (DSOFF) + 4096 + w * 512),   \
        16, 0, 0);                                                                            \
  } while (0)

// ---- one BK=32 MFMA step on a 256x256 tile: 8 waves (2Mx4N), 8x4 frags/wave ----
__device__ __forceinline__ void mma256(const unsigned short* smem, int abuf, int bbuf,
                                       int wr, int wc, int r, int q, int sbq, f32x4 acc[8][4]) {
  s16x8 bf[4];
  #pragma unroll
  for (int j = 0; j < 4; ++j)
    bf[j] = *(const s16x8*)(smem + bbuf + (wc * 64 + j * 16 + r) * 32 + sbq);
  #pragma unroll
  for (int i = 0; i < 8; ++i) {
    const s16x8 af = *(const s16x8*)(smem + abuf + (wr * 128 + i * 16 + r) * 32 + sbq);
    #pragma unroll
    for (int j = 0; j < 4; ++j)
      acc[i][j] = MFMA16(af, bf[j], acc[i][j]);
  }
}

// ---------------- proj: f_all[24576][512] = [feat;ex_feat] @ g_w^T + g_b ----------------
__global__ __launch_bounds__(512, 2) void k_proj(const unsigned short* __restrict__ featbf,
                                                 const unsigned short* __restrict__ exbf,
                                                 const unsigned short* __restrict__ gwbf,
                                                 const float* __restrict__ gb,
                                                 float* __restrict__ fall) {
  __shared__ __align__(16) unsigned short smem[32768];  // A0|B0|A1|B1 @ 0,8192,16384,24576
  const int tid = threadIdx.x, w = tid >> 6, lane = tid & 63;
  const int wr = w >> 2, wc = w & 3, r = lane & 15, q = lane >> 4;
  const int sbq = (q ^ ((r >> 1) & 3)) << 3;
  const int rowL = w * 16 + (lane >> 2);
  const int offsrc = rowL * 1024 + (((lane & 3) ^ ((rowL >> 1) & 3)) << 3);
  const int m0 = blockIdx.x * 256;
  const int n0 = blockIdx.y * 256;
  const unsigned short* Asrc = (m0 < 8192) ? (featbf + (size_t)m0 * 1024)
                                           : (exbf + (size_t)(m0 - 8192) * 1024);
  const unsigned short* Bsrc = gwbf + (size_t)n0 * 1024;
  f32x4 acc[8][4];
  #pragma unroll
  for (int i = 0; i < 8; ++i)
    #pragma unroll
    for (int j = 0; j < 4; ++j) acc[i][j] = {0.f, 0.f, 0.f, 0.f};

  STAGE(Asrc, 1024, 0); STAGE(Bsrc, 1024, 8192);      // K-step 0 -> buf0
  for (int t = 0; t < 31; ++t) {
    const int nb = ((t + 1) & 1) * 16384;
    STAGE(Asrc + (t + 1) * 32, 1024, nb);
    STAGE(Bsrc + (t + 1) * 32, 1024, nb + 8192);
    WAIT_VM(4);                                       // step t landed; t+1's 4 in flight
    BAR();
    mma256(smem, (t & 1) * 16384, (t & 1) * 16384 + 8192, wr, wc, r, q, sbq, acc);
    WAIT_LGKM();
    BAR();
  }
  WAIT_VM(0);
  BAR();
  mma256(smem, 16384, 24576, wr, wc, r, q, sbq, acc); // step 31 (buf1)

  #pragma unroll
  for (int j = 0; j < 4; ++j) {
    const int col = n0 + wc * 64 + j * 16 + r;
    const float bias = gb[col];
    #pragma unroll
    for (int i = 0; i < 8; ++i) {
      const int row0 = m0 + wr * 128 + i * 16 + q * 4;
      #pragma unroll
      for (int t = 0; t < 4; ++t)
        fall[(size_t)(row0 + t) * 512 + col] = acc[i][j][t] + bias;
    }
  }
}

// ---------------- normalize rows of f_all (512) -> bf16 fn_all ----------------
__global__ __launch_bounds__(256) void k_norm(const float* __restrict__ fall,
                                              unsigned short* __restrict__ fn) {
  const int row = blockIdx.x * 4 + (threadIdx.x >> 6);
  const int lane = threadIdx.x & 63;
  const float4* p = (const float4*)(fall + (size_t)row * 512) + lane * 2;
  const float4 v0 = p[0], v1 = p[1];
  float ss = v0.x * v0.x + v0.y * v0.y + v0.z * v0.z + v0.w * v0.w
           + v1.x * v1.x + v1.y * v1.y + v1.z * v1.z + v1.w * v1.w;
  #pragma unroll
  for (int o = 32; o; o >>= 1) ss += __shfl_xor(ss, o, 64);
  const float sc = 1.0f / fmaxf(sqrtf(ss), 1e-12f);
  ushort4 o0, o1;
  o0.x = f2bf(v0.x * sc); o0.y = f2bf(v0.y * sc); o0.z = f2bf(v0.z * sc); o0.w = f2bf(v0.w * sc);
  o1.x = f2bf(v1.x * sc); o1.y = f2bf(v1.y * sc); o1.z = f2bf(v1.z * sc); o1.w = f2bf(v1.w * sc);
  ushort4* qo = (ushort4*)(fn + (size_t)row * 512) + lane * 2;
  qo[0] = o0; qo[1] = o1;
}

// ---------------- fused: s = fn @ efn^T (256^2 tile), a = s^3, echo += a @ excT^T ----------------
__global__ __launch_bounds__(512, 2) void k_fused(const unsigned short* __restrict__ fnall,
                                                  const unsigned short* __restrict__ excT,
                                                  float* __restrict__ partial) {
  __shared__ __align__(16) unsigned short smem[32768];  // A0|B0|A1|B1; aL aliases all (time-disjoint)
  unsigned short* aL = smem;                            // [128][256] bf16, block-XOR swizzled
  const int tid = threadIdx.x, w = tid >> 6, lane = tid & 63;
  const int wr = w >> 2, wc = w & 3, r = lane & 15, q = lane >> 4;
  const int sbq = (q ^ ((r >> 1) & 3)) << 3;
  const int rowL = w * 16 + (lane >> 2);
  const int offsrc = rowL * 512 + (((lane & 3) ^ ((rowL >> 1) & 3)) << 3);
  const int r0 = blockIdx.x * 256;     // 32 M-tiles
  const int nchunk = blockIdx.y;       // 16 N-chunks of 4 j-tiles (256 wide each)
  const unsigned short* Abase = fnall + (size_t)r0 * 512;
  const unsigned short* Ebase = fnall + (size_t)8192 * 512;
  f32x4 eacc[2][2];                    // [row-half][cls-frag]
  #pragma unroll
  for (int a = 0; a < 2; ++a)
    #pragma unroll
    for (int b = 0; b < 2; ++b) eacc[a][b] = {0.f, 0.f, 0.f, 0.f};

  // prologue: jt=0, K-step 0 -> buf0
  STAGE(Abase, 512, 0);
  STAGE(Ebase + (size_t)(nchunk * 4) * 256 * 512, 512, 8192);

  for (int jt = 0; jt < 4; ++jt) {
    const int c0 = (nchunk * 4 + jt) * 256;
    const unsigned short* Bsrc = Ebase + (size_t)c0 * 512;
    f32x4 acc[8][4];
    #pragma unroll
    for (int i = 0; i < 8; ++i)
      #pragma unroll
      for (int j = 0; j < 4; ++j) acc[i][j] = {0.f, 0.f, 0.f, 0.f};

    for (int t = 0; t < 15; ++t) {
      const int nb = ((t + 1) & 1) * 16384;
      STAGE(Abase + (t + 1) * 32, 512, nb);
      STAGE(Bsrc + (t + 1) * 32, 512, nb + 8192);
      WAIT_VM(4);
      BAR();
      mma256(smem, (t & 1) * 16384, (t & 1) * 16384 + 8192, wr, wc, r, q, sbq, acc);
      WAIT_LGKM();
      BAR();
    }
    WAIT_VM(0);
    BAR();
    mma256(smem, 16384, 24576, wr, wc, r, q, sbq, acc);  // K-step 15 (buf1)
    WAIT_LGKM();
    BAR();                              // all staging-buffer reads done -> aL writable

    // echo in two row-halves of 128 (aL = [128][256] aliases the staging buffers)
    #pragma unroll
    for (int h = 0; h < 2; ++h) {
      if (wr == h) {
        // cube own 128x64 block into aL; elem col swizzle: blk' = blk ^ (row&7)
        #pragma unroll
        for (int i = 0; i < 8; ++i)
          #pragma unroll
          for (int j = 0; j < 4; ++j) {
            const int rh0 = i * 16 + q * 4;
            const int col = wc * 64 + j * 16 + r;
            const int cb = col >> 3, cl = col & 7;
            #pragma unroll
            for (int t2 = 0; t2 < 4; ++t2) {
              const int row = rh0 + t2;
              const float v = acc[i][j][t2];
              aL[row * 256 + (((cb ^ (row & 7)) << 3) | cl)] = f2bf(v * v * v);
            }
          }
      }
      WAIT_LGKM();
      BAR();
      // echo MFMA: wave w owns rows w*16..+15 of this half; K=256, N=32
      {
        const int rowE = w * 16 + r;
        const int swe = r & 7;
        #pragma unroll
        for (int kc = 0; kc < 8; ++kc) {
          const s16x8 af2 = *(const s16x8*)(aL + rowE * 256 + (((kc * 4 + q) ^ swe) << 3));
          #pragma unroll
          for (int nj = 0; nj < 2; ++nj) {
            const s16x8 bfr = *(const s16x8*)(excT + (size_t)(nj * 16 + r) * 16384 + c0 + kc * 32 + q * 8);
            eacc[h][nj] = MFMA16(af2, bfr, eacc[h][nj]);
          }
        }
      }
      WAIT_LGKM();
      BAR();                            // aL reads done -> next half / next stage may overwrite
    }
    if (jt < 3) {                       // prefetch next j-tile's K-step 0 -> buf0
      const unsigned short* Bn = Ebase + (size_t)((nchunk * 4 + jt + 1) * 256) * 512;
      STAGE(Abase, 512, 0);
      STAGE(Bn, 512, 8192);
    }
  }
  // write partial [nchunk][8192][32]
  #pragma unroll
  for (int h = 0; h < 2; ++h)
    #pragma unroll
    for (int nj = 0; nj < 2; ++nj) {
      const int rb = r0 + h * 128 + w * 16 + q * 4;
      const int cls = nj * 16 + r;
      #pragma unroll
      for (int t = 0; t < 4; ++t)
        partial[((size_t)nchunk * 8192 + rb + t) * 32 + cls] = eacc[h][nj][t];
    }
}

// ---------------- reduce 16 partials, /b, clip ----------------
__global__ void k_reduce(const float* __restrict__ partial, const float* __restrict__ bvec,
                         float* __restrict__ out) {
  const int idx = blockIdx.x * 256 + threadIdx.x;  // 229376 total
  const int row = idx / 28, c = idx - row * 28;
  float s = 0.f;
  #pragma unroll
  for (int nc = 0; nc < 16; ++nc) s += partial[((size_t)nc * 8192 + row) * 32 + c];
  out[idx] = fminf(fmaxf(s / bvec[c], 0.f), 1.f);
}

extern "C" void kernel_launch(void* const* d_in, const int* in_sizes, int n_in,
                              void* d_out, int out_size, void* d_ws, size_t ws_size,
                              hipStream_t stream) {
  const float* features    = (const float*)d_in[0];  // [8192,1024]
  const float* ex_features = (const float*)d_in[1];  // [16384,1024]
  const float* g_w         = (const float*)d_in[2];  // [512,1024]
  const float* g_b         = (const float*)d_in[3];  // [512]
  const float* ex_classes  = (const float*)d_in[4];  // [16384,28]
  float* out = (float*)d_out;
  char* ws = (char*)d_ws;

  unsigned short* featbf = (unsigned short*)(ws + 0);
  unsigned short* exbf   = (unsigned short*)(ws + 16777216);
  unsigned short* fnall  = (unsigned short*)(ws + 0);
  float* fall            = (float*)(ws + 50331648);
  float* partial         = (float*)(ws + 50331648);
  unsigned short* gwbf   = (unsigned short*)(ws + 100663296);
  unsigned short* excT   = (unsigned short*)(ws + 101711872);
  float* bvec            = (float*)(ws + 102760448);

  k_cast_bf16<<<2048, 256, 0, stream>>>(features, featbf, 8192 * 1024 / 4);
  k_cast_bf16<<<2048, 256, 0, stream>>>(ex_features, exbf, 16384 * 1024 / 4);
  k_cast_bf16<<<512, 256, 0, stream>>>(g_w, gwbf, 512 * 1024 / 4);
  k_excT<<<32, 256, 0, stream>>>(ex_classes, excT, bvec);
  k_proj<<<dim3(96, 2), 512, 0, stream>>>(featbf, exbf, gwbf, g_b, fall);
  k_norm<<<6144, 256, 0, stream>>>(fall, fnall);
  k_fused<<<dim3(32, 16), 512, 0, stream>>>(fnall, excT, partial);
  k_reduce<<<896, 256, 0, stream>>>(partial, bvec, out);
}

// Round 5
// 368.611 us; speedup vs baseline: 1.9329x; 1.9329x over previous
//
#include <hip/hip_runtime.h>
#include <stdint.h>

typedef __attribute__((ext_vector_type(4))) float f32x4;
typedef __attribute__((ext_vector_type(8))) short s16x8;

#define MFMA16(A, B, C) __builtin_amdgcn_mfma_f32_16x16x32_bf16(A, B, C, 0, 0, 0)
#define WAIT_VM(N) asm volatile("s_waitcnt vmcnt(" #N ")" ::: "memory")
#define WAIT_LGKM() asm volatile("s_waitcnt lgkmcnt(0)" ::: "memory")
#define BAR() __builtin_amdgcn_s_barrier()

__device__ __forceinline__ unsigned short f2bf(float x) {
  union { float f; unsigned u; } v; v.f = x;
  return (unsigned short)((v.u + 0x7fffu + ((v.u >> 16) & 1u)) >> 16);
}

// ---------------- cast f32 -> bf16, 4 elems/thread ----------------
__global__ void k_cast_bf16(const float* __restrict__ in, unsigned short* __restrict__ out, int n4) {
  int i = blockIdx.x * blockDim.x + threadIdx.x;
  const int stride = gridDim.x * blockDim.x;
  for (; i < n4; i += stride) {
    const float4 v = ((const float4*)in)[i];
    ushort4 o;
    o.x = f2bf(v.x); o.y = f2bf(v.y); o.z = f2bf(v.z); o.w = f2bf(v.w);
    ((ushort4*)out)[i] = o;
  }
}

// ---------------- exc [16384][28] -> excT bf16 [32][16384] (rows 28..31 = 0) + b[28] ----------------
__global__ void k_excT(const float* __restrict__ exc, unsigned short* __restrict__ excT,
                       float* __restrict__ bvec) {
  const int c = blockIdx.x;        // 0..31
  const int tid = threadIdx.x;     // 256
  float sum = 0.f;
  for (int j = tid; j < 16384; j += 256) {
    const float v = (c < 28) ? exc[(size_t)j * 28 + c] : 0.f;
    excT[(size_t)c * 16384 + j] = f2bf(v);
    sum += v;
  }
  #pragma unroll
  for (int o = 32; o; o >>= 1) sum += __shfl_down(sum, o, 64);
  __shared__ float wsum[4];
  if ((tid & 63) == 0) wsum[tid >> 6] = sum;
  __syncthreads();
  if (tid == 0 && c < 28) bvec[c] = fmaxf(wsum[0] + wsum[1] + wsum[2] + wsum[3], 1.0f);
}

// ---- stage 256x64 (A) / 128x64 (B) bf16 tiles into LDS, XOR-swizzled source ----
// LDS[row][blk] = G[row][blk ^ (row&7)] (8 x 16B blocks per 64-col row); dest linear.
// offsrc = (w*8 + lane>>3)*ld + ((lane&7)^(lane>>3))*8 ; thread covers rows +c*64.
__device__ __forceinline__ void stage_a(const unsigned short* __restrict__ src, int ld,
                                        unsigned short* smem, int dsoff, int w, int offsrc) {
  #pragma unroll
  for (int c = 0; c < 4; ++c)
    __builtin_amdgcn_global_load_lds(
        (const __attribute__((address_space(1))) unsigned int*)(src + offsrc + c * 64 * ld),
        (__attribute__((address_space(3))) unsigned int*)(smem + dsoff + c * 4096 + w * 512),
        16, 0, 0);
}
__device__ __forceinline__ void stage_b(const unsigned short* __restrict__ src, int ld,
                                        unsigned short* smem, int dsoff, int w, int offsrc) {
  #pragma unroll
  for (int c = 0; c < 2; ++c)
    __builtin_amdgcn_global_load_lds(
        (const __attribute__((address_space(1))) unsigned int*)(src + offsrc + c * 64 * ld),
        (__attribute__((address_space(3))) unsigned int*)(smem + dsoff + c * 4096 + w * 512),
        16, 0, 0);
}

// ---- one BK=64 MFMA step on a 256x128 tile: 8 waves (2M x 4N), acc[8][2] ----
__device__ __forceinline__ void mma_step(const unsigned short* smem, int ao, int bo,
                                         int wr, int wc, int r, int q, f32x4 acc[8][2]) {
  const int rx = r & 7;
  #pragma unroll
  for (int ks = 0; ks < 2; ++ks) {
    const int sb = ((ks * 4 + q) ^ rx) << 3;
    s16x8 bf[2];
    #pragma unroll
    for (int j = 0; j < 2; ++j)
      bf[j] = *(const s16x8*)(smem + bo + (wc * 32 + j * 16 + r) * 64 + sb);
    #pragma unroll
    for (int i = 0; i < 8; ++i) {
      const s16x8 af = *(const s16x8*)(smem + ao + (wr * 128 + i * 16 + r) * 64 + sb);
      #pragma unroll
      for (int j = 0; j < 2; ++j)
        acc[i][j] = MFMA16(af, bf[j], acc[i][j]);
    }
  }
}

// LDS layout (shorts): A0@0(16384) B0@16384(8192) A1@24576(16384) B1@40960(8192)
#define A0 0
#define B0 16384
#define A1 24576
#define B1 40960

// ---------------- proj: f_all[24576][512] = [feat;ex_feat] @ g_w^T + g_b ----------------
__global__ __launch_bounds__(512, 2) void k_proj(const unsigned short* __restrict__ featbf,
                                                 const unsigned short* __restrict__ exbf,
                                                 const unsigned short* __restrict__ gwbf,
                                                 const float* __restrict__ gb,
                                                 float* __restrict__ fall) {
  __shared__ __align__(16) unsigned short smem[49152];  // 96 KB
  const int tid = threadIdx.x, w = tid >> 6, lane = tid & 63;
  const int wr = w >> 2, wc = w & 3, r = lane & 15, q = lane >> 4;
  const int offsrc = (w * 8 + (lane >> 3)) * 1024 + (((lane & 7) ^ (lane >> 3)) << 3);
  const int m0 = blockIdx.x * 256;
  const int n0 = blockIdx.y * 128;
  const unsigned short* Asrc = (m0 < 8192) ? (featbf + (size_t)m0 * 1024)
                                           : (exbf + (size_t)(m0 - 8192) * 1024);
  const unsigned short* Bsrc = gwbf + (size_t)n0 * 1024;
  f32x4 acc[8][2];
  #pragma unroll
  for (int i = 0; i < 8; ++i)
    #pragma unroll
    for (int j = 0; j < 2; ++j) acc[i][j] = {0.f, 0.f, 0.f, 0.f};

  stage_a(Asrc, 1024, smem, A0, w, offsrc);
  stage_b(Bsrc, 1024, smem, B0, w, offsrc);
  for (int t = 0; t < 15; ++t) {
    const int na = ((t + 1) & 1) ? A1 : A0, nbb = ((t + 1) & 1) ? B1 : B0;
    stage_a(Asrc + (t + 1) * 64, 1024, smem, na, w, offsrc);
    stage_b(Bsrc + (t + 1) * 64, 1024, smem, nbb, w, offsrc);
    WAIT_VM(6);                              // step t landed; t+1's 6 in flight
    BAR();
    mma_step(smem, (t & 1) ? A1 : A0, (t & 1) ? B1 : B0, wr, wc, r, q, acc);
    WAIT_LGKM();
    BAR();
  }
  WAIT_VM(0);
  BAR();
  mma_step(smem, A1, B1, wr, wc, r, q, acc); // step 15 (odd -> buf1)

  #pragma unroll
  for (int j = 0; j < 2; ++j) {
    const int col = n0 + wc * 32 + j * 16 + r;
    const float bias = gb[col];
    #pragma unroll
    for (int i = 0; i < 8; ++i) {
      const int row0 = m0 + wr * 128 + i * 16 + q * 4;
      #pragma unroll
      for (int t = 0; t < 4; ++t)
        fall[(size_t)(row0 + t) * 512 + col] = acc[i][j][t] + bias;
    }
  }
}

// ---------------- normalize rows of f_all (512) -> bf16 fn_all ----------------
__global__ __launch_bounds__(256) void k_norm(const float* __restrict__ fall,
                                              unsigned short* __restrict__ fn) {
  const int row = blockIdx.x * 4 + (threadIdx.x >> 6);
  const int lane = threadIdx.x & 63;
  const float4* p = (const float4*)(fall + (size_t)row * 512) + lane * 2;
  const float4 v0 = p[0], v1 = p[1];
  float ss = v0.x * v0.x + v0.y * v0.y + v0.z * v0.z + v0.w * v0.w
           + v1.x * v1.x + v1.y * v1.y + v1.z * v1.z + v1.w * v1.w;
  #pragma unroll
  for (int o = 32; o; o >>= 1) ss += __shfl_xor(ss, o, 64);
  const float sc = 1.0f / fmaxf(sqrtf(ss), 1e-12f);
  ushort4 o0, o1;
  o0.x = f2bf(v0.x * sc); o0.y = f2bf(v0.y * sc); o0.z = f2bf(v0.z * sc); o0.w = f2bf(v0.w * sc);
  o1.x = f2bf(v1.x * sc); o1.y = f2bf(v1.y * sc); o1.z = f2bf(v1.z * sc); o1.w = f2bf(v1.w * sc);
  ushort4* qo = (ushort4*)(fn + (size_t)row * 512) + lane * 2;
  qo[0] = o0; qo[1] = o1;
}

// ---------------- fused: s-tile 256x128, a = s^3, echo += a @ excT^T ----------------
__global__ __launch_bounds__(512, 2) void k_fused(const unsigned short* __restrict__ fnall,
                                                  const unsigned short* __restrict__ excT,
                                                  float* __restrict__ partial) {
  __shared__ __align__(16) unsigned short smem[65536];  // 96 KB staging + 32 KB aL = 128 KB
  unsigned short* aL = smem + 49152;                    // [128][128] bf16, block-XOR swizzled
  const int tid = threadIdx.x, w = tid >> 6, lane = tid & 63;
  const int wr = w >> 2, wc = w & 3, r = lane & 15, q = lane >> 4;
  const int offsrc = (w * 8 + (lane >> 3)) * 512 + (((lane & 7) ^ (lane >> 3)) << 3);
  const int r0 = blockIdx.x * 256;     // 32 M-tiles
  const int nchunk = blockIdx.y;       // 16 N-chunks of 8 j-tiles (128 wide each)
  const unsigned short* Abase = fnall + (size_t)r0 * 512;
  const unsigned short* Ebase = fnall + (size_t)8192 * 512;
  f32x4 eacc[2][2];                    // [row-half][cls-frag]
  #pragma unroll
  for (int a = 0; a < 2; ++a)
    #pragma unroll
    for (int b = 0; b < 2; ++b) eacc[a][b] = {0.f, 0.f, 0.f, 0.f};

  // prologue: jt=0 step0 -> buf0
  stage_a(Abase, 512, smem, A0, w, offsrc);
  stage_b(Ebase + (size_t)(nchunk * 8) * 128 * 512, 512, smem, B0, w, offsrc);

  for (int jt = 0; jt < 8; ++jt) {
    const int c0 = (nchunk * 8 + jt) * 128;
    const unsigned short* Bsrc = Ebase + (size_t)c0 * 512;
    f32x4 acc[8][2];
    #pragma unroll
    for (int i = 0; i < 8; ++i)
      #pragma unroll
      for (int j = 0; j < 2; ++j) acc[i][j] = {0.f, 0.f, 0.f, 0.f};

    for (int t = 0; t < 7; ++t) {      // K=512 -> 8 steps of BK=64
      const int na = ((t + 1) & 1) ? A1 : A0, nbb = ((t + 1) & 1) ? B1 : B0;
      stage_a(Abase + (t + 1) * 64, 512, smem, na, w, offsrc);
      stage_b(Bsrc + (t + 1) * 64, 512, smem, nbb, w, offsrc);
      WAIT_VM(6);
      BAR();
      __builtin_amdgcn_s_setprio(1);
      mma_step(smem, (t & 1) ? A1 : A0, (t & 1) ? B1 : B0, wr, wc, r, q, acc);
      __builtin_amdgcn_s_setprio(0);
      WAIT_LGKM();
      BAR();                           // buf[t&1] free
    }
    // prefetch next jt's step0 into buf0 (buf0 free since t=6); overlaps final mma + cube + echo
    if (jt < 7) {
      stage_a(Abase, 512, smem, A0, w, offsrc);
      stage_b(Bsrc + (size_t)128 * 512, 512, smem, B0, w, offsrc);  // next j-tile's B panel
      WAIT_VM(6);                      // step7's 6 landed; prefetch stays in flight
    } else {
      WAIT_VM(0);
    }
    BAR();
    __builtin_amdgcn_s_setprio(1);
    mma_step(smem, A1, B1, wr, wc, r, q, acc);   // step 7 (buf1)
    __builtin_amdgcn_s_setprio(0);
    WAIT_LGKM();
    BAR();

    // echo in two row-halves of 128 via aL (separate 32 KB region — no staging alias)
    #pragma unroll
    for (int h = 0; h < 2; ++h) {
      if (wr == h) {                   // 4 waves cube-write their 128x32 block
        #pragma unroll
        for (int i = 0; i < 8; ++i)
          #pragma unroll
          for (int j = 0; j < 2; ++j) {
            const int colc = wc * 32 + j * 16 + r;
            const int cb = colc >> 3, cl = colc & 7;
            #pragma unroll
            for (int t2 = 0; t2 < 4; ++t2) {
              const int row = i * 16 + q * 4 + t2;
              const float v = acc[i][j][t2];
              aL[row * 128 + ((((cb & 8) | ((cb ^ (row & 7)) & 7)) << 3) | cl)] = f2bf(v * v * v);
            }
          }
      }
      WAIT_LGKM();
      BAR();
      // echo MFMA: wave w owns rows w*16..+15 of this half; K=128, N=32
      {
        const int rowE = w * 16 + r;
        const int rx8 = r & 7;
        #pragma unroll
        for (int kc = 0; kc < 4; ++kc) {
          const int kb = kc * 4 + q;
          const s16x8 af2 = *(const s16x8*)(aL + rowE * 128 + (((kb & 8) | ((kb ^ rx8) & 7)) << 3));
          #pragma unroll
          for (int nj = 0; nj < 2; ++nj) {
            const s16x8 bfr = *(const s16x8*)(excT + (size_t)(nj * 16 + r) * 16384 + c0 + kc * 32 + q * 8);
            eacc[h][nj] = MFMA16(af2, bfr, eacc[h][nj]);
          }
        }
      }
      WAIT_LGKM();
      BAR();                           // aL reads done -> next half may overwrite
    }
  }
  // write partial [nchunk][8192][32]
  #pragma unroll
  for (int h = 0; h < 2; ++h)
    #pragma unroll
    for (int nj = 0; nj < 2; ++nj) {
      const int rb = r0 + h * 128 + w * 16 + q * 4;
      const int cls = nj * 16 + r;
      #pragma unroll
      for (int t = 0; t < 4; ++t)
        partial[((size_t)nchunk * 8192 + rb + t) * 32 + cls] = eacc[h][nj][t];
    }
}

// ---------------- reduce 16 partials, /b, clip ----------------
__global__ void k_reduce(const float* __restrict__ partial, const float* __restrict__ bvec,
                         float* __restrict__ out) {
  const int idx = blockIdx.x * 256 + threadIdx.x;  // 229376 total
  const int row = idx / 28, c = idx - row * 28;
  float s = 0.f;
  #pragma unroll
  for (int nc = 0; nc < 16; ++nc) s += partial[((size_t)nc * 8192 + row) * 32 + c];
  out[idx] = fminf(fmaxf(s / bvec[c], 0.f), 1.f);
}

extern "C" void kernel_launch(void* const* d_in, const int* in_sizes, int n_in,
                              void* d_out, int out_size, void* d_ws, size_t ws_size,
                              hipStream_t stream) {
  const float* features    = (const float*)d_in[0];  // [8192,1024]
  const float* ex_features = (const float*)d_in[1];  // [16384,1024]
  const float* g_w         = (const float*)d_in[2];  // [512,1024]
  const float* g_b         = (const float*)d_in[3];  // [512]
  const float* ex_classes  = (const float*)d_in[4];  // [16384,28]
  float* out = (float*)d_out;
  char* ws = (char*)d_ws;

  unsigned short* featbf = (unsigned short*)(ws + 0);
  unsigned short* exbf   = (unsigned short*)(ws + 16777216);
  unsigned short* fnall  = (unsigned short*)(ws + 0);
  float* fall            = (float*)(ws + 50331648);
  float* partial         = (float*)(ws + 50331648);
  unsigned short* gwbf   = (unsigned short*)(ws + 100663296);
  unsigned short* excT   = (unsigned short*)(ws + 101711872);
  float* bvec            = (float*)(ws + 102760448);

  k_cast_bf16<<<2048, 256, 0, stream>>>(features, featbf, 8192 * 1024 / 4);
  k_cast_bf16<<<2048, 256, 0, stream>>>(ex_features, exbf, 16384 * 1024 / 4);
  k_cast_bf16<<<512, 256, 0, stream>>>(g_w, gwbf, 512 * 1024 / 4);
  k_excT<<<32, 256, 0, stream>>>(ex_classes, excT, bvec);
  k_proj<<<dim3(96, 4), 512, 0, stream>>>(featbf, exbf, gwbf, g_b, fall);
  k_norm<<<6144, 256, 0, stream>>>(fall, fnall);
  k_fused<<<dim3(32, 16), 512, 0, stream>>>(fnall, excT, partial);
  k_reduce<<<896, 256, 0, stream>>>(partial, bvec, out);
}

// Round 6
// 255.609 us; speedup vs baseline: 2.7874x; 1.4421x over previous
//
#include <hip/hip_runtime.h>
#include <stdint.h>

typedef __attribute__((ext_vector_type(4))) float f32x4;
typedef __attribute__((ext_vector_type(8))) short s16x8;

#define MFMA16(A, B, C) __builtin_amdgcn_mfma_f32_16x16x32_bf16(A, B, C, 0, 0, 0)
#define WAIT_VM(N) asm volatile("s_waitcnt vmcnt(" #N ")" ::: "memory")
#define WAIT_LGKM() asm volatile("s_waitcnt lgkmcnt(0)" ::: "memory")
#define BAR() __builtin_amdgcn_s_barrier()
#define SCHED_FENCE() __builtin_amdgcn_sched_barrier(0)
#define SP1() __builtin_amdgcn_s_setprio(1)
#define SP0() __builtin_amdgcn_s_setprio(0)

// phase sync: pin, drain own ds ops, counted vm wait, barrier, pin.
#define PHASE_SYNC(N) do { SCHED_FENCE(); WAIT_LGKM(); WAIT_VM(N); BAR(); SCHED_FENCE(); } while (0)
#define PHASE_SYNC_NOVM() do { SCHED_FENCE(); WAIT_LGKM(); BAR(); SCHED_FENCE(); } while (0)

__device__ __forceinline__ unsigned short f2bf(float x) {
  union { float f; unsigned u; } v; v.f = x;
  return (unsigned short)((v.u + 0x7fffu + ((v.u >> 16) & 1u)) >> 16);
}

// ---------------- cast f32 -> bf16, 4 elems/thread ----------------
__global__ void k_cast_bf16(const float* __restrict__ in, unsigned short* __restrict__ out, int n4) {
  int i = blockIdx.x * blockDim.x + threadIdx.x;
  const int stride = gridDim.x * blockDim.x;
  for (; i < n4; i += stride) {
    const float4 v = ((const float4*)in)[i];
    ushort4 o;
    o.x = f2bf(v.x); o.y = f2bf(v.y); o.z = f2bf(v.z); o.w = f2bf(v.w);
    ((ushort4*)out)[i] = o;
  }
}

// ---------------- exc [16384][28] -> excT bf16 [32][16384] (rows 28..31 = 0) + b[28] ----------------
__global__ void k_excT(const float* __restrict__ exc, unsigned short* __restrict__ excT,
                       float* __restrict__ bvec) {
  const int c = blockIdx.x;        // 0..31
  const int tid = threadIdx.x;     // 256
  float sum = 0.f;
  for (int j = tid; j < 16384; j += 256) {
    const float v = (c < 28) ? exc[(size_t)j * 28 + c] : 0.f;
    excT[(size_t)c * 16384 + j] = f2bf(v);
    sum += v;
  }
  #pragma unroll
  for (int o = 32; o; o >>= 1) sum += __shfl_down(sum, o, 64);
  __shared__ float wsum[4];
  if ((tid & 63) == 0) wsum[tid >> 6] = sum;
  __syncthreads();
  if (tid == 0 && c < 28) bvec[c] = fmaxf(wsum[0] + wsum[1] + wsum[2] + wsum[3], 1.0f);
}

// ================= k_proj (R5 engine, unchanged) =================
__device__ __forceinline__ void stage_a(const unsigned short* __restrict__ src, int ld,
                                        unsigned short* smem, int dsoff, int w, int offsrc) {
  #pragma unroll
  for (int c = 0; c < 4; ++c)
    __builtin_amdgcn_global_load_lds(
        (const __attribute__((address_space(1))) unsigned int*)(src + offsrc + c * 64 * ld),
        (__attribute__((address_space(3))) unsigned int*)(smem + dsoff + c * 4096 + w * 512),
        16, 0, 0);
}
__device__ __forceinline__ void stage_b(const unsigned short* __restrict__ src, int ld,
                                        unsigned short* smem, int dsoff, int w, int offsrc) {
  #pragma unroll
  for (int c = 0; c < 2; ++c)
    __builtin_amdgcn_global_load_lds(
        (const __attribute__((address_space(1))) unsigned int*)(src + offsrc + c * 64 * ld),
        (__attribute__((address_space(3))) unsigned int*)(smem + dsoff + c * 4096 + w * 512),
        16, 0, 0);
}

__device__ __forceinline__ void mma_step_p(const unsigned short* smem, int ao, int bo,
                                           int wr, int wc, int r, int q, f32x4 acc[8][2]) {
  const int rx = r & 7;
  #pragma unroll
  for (int ks = 0; ks < 2; ++ks) {
    const int sb = ((ks * 4 + q) ^ rx) << 3;
    s16x8 bf[2];
    #pragma unroll
    for (int j = 0; j < 2; ++j)
      bf[j] = *(const s16x8*)(smem + bo + (wc * 32 + j * 16 + r) * 64 + sb);
    #pragma unroll
    for (int i = 0; i < 8; ++i) {
      const s16x8 af = *(const s16x8*)(smem + ao + (wr * 128 + i * 16 + r) * 64 + sb);
      #pragma unroll
      for (int j = 0; j < 2; ++j)
        acc[i][j] = MFMA16(af, bf[j], acc[i][j]);
    }
  }
}

#define PA0 0
#define PB0 16384
#define PA1 24576
#define PB1 40960

__global__ __launch_bounds__(512, 2) void k_proj(const unsigned short* __restrict__ featbf,
                                                 const unsigned short* __restrict__ exbf,
                                                 const unsigned short* __restrict__ gwbf,
                                                 const float* __restrict__ gb,
                                                 float* __restrict__ fall) {
  __shared__ __align__(16) unsigned short smem[49152];  // 96 KB
  const int tid = threadIdx.x, w = tid >> 6, lane = tid & 63;
  const int wr = w >> 2, wc = w & 3, r = lane & 15, q = lane >> 4;
  const int offsrc = (w * 8 + (lane >> 3)) * 1024 + (((lane & 7) ^ (lane >> 3)) << 3);
  const int m0 = blockIdx.x * 256;
  const int n0 = blockIdx.y * 128;
  const unsigned short* Asrc = (m0 < 8192) ? (featbf + (size_t)m0 * 1024)
                                           : (exbf + (size_t)(m0 - 8192) * 1024);
  const unsigned short* Bsrc = gwbf + (size_t)n0 * 1024;
  f32x4 acc[8][2];
  #pragma unroll
  for (int i = 0; i < 8; ++i)
    #pragma unroll
    for (int j = 0; j < 2; ++j) acc[i][j] = {0.f, 0.f, 0.f, 0.f};

  stage_a(Asrc, 1024, smem, PA0, w, offsrc);
  stage_b(Bsrc, 1024, smem, PB0, w, offsrc);
  for (int t = 0; t < 15; ++t) {
    const int na = ((t + 1) & 1) ? PA1 : PA0, nbb = ((t + 1) & 1) ? PB1 : PB0;
    stage_a(Asrc + (t + 1) * 64, 1024, smem, na, w, offsrc);
    stage_b(Bsrc + (t + 1) * 64, 1024, smem, nbb, w, offsrc);
    WAIT_VM(6);
    BAR();
    mma_step_p(smem, (t & 1) ? PA1 : PA0, (t & 1) ? PB1 : PB0, wr, wc, r, q, acc);
    WAIT_LGKM();
    BAR();
  }
  WAIT_VM(0);
  BAR();
  mma_step_p(smem, PA1, PB1, wr, wc, r, q, acc);

  #pragma unroll
  for (int j = 0; j < 2; ++j) {
    const int col = n0 + wc * 32 + j * 16 + r;
    const float bias = gb[col];
    #pragma unroll
    for (int i = 0; i < 8; ++i) {
      const int row0 = m0 + wr * 128 + i * 16 + q * 4;
      #pragma unroll
      for (int t = 0; t < 4; ++t)
        fall[(size_t)(row0 + t) * 512 + col] = acc[i][j][t] + bias;
    }
  }
}

// ---------------- normalize rows of f_all (512) -> bf16 fn_all ----------------
__global__ __launch_bounds__(256) void k_norm(const float* __restrict__ fall,
                                              unsigned short* __restrict__ fn) {
  const int row = blockIdx.x * 4 + (threadIdx.x >> 6);
  const int lane = threadIdx.x & 63;
  const float4* p = (const float4*)(fall + (size_t)row * 512) + lane * 2;
  const float4 v0 = p[0], v1 = p[1];
  float ss = v0.x * v0.x + v0.y * v0.y + v0.z * v0.z + v0.w * v0.w
           + v1.x * v1.x + v1.y * v1.y + v1.z * v1.z + v1.w * v1.w;
  #pragma unroll
  for (int o = 32; o; o >>= 1) ss += __shfl_xor(ss, o, 64);
  const float sc = 1.0f / fmaxf(sqrtf(ss), 1e-12f);
  ushort4 o0, o1;
  o0.x = f2bf(v0.x * sc); o0.y = f2bf(v0.y * sc); o0.z = f2bf(v0.z * sc); o0.w = f2bf(v0.w * sc);
  o1.x = f2bf(v1.x * sc); o1.y = f2bf(v1.y * sc); o1.z = f2bf(v1.z * sc); o1.w = f2bf(v1.w * sc);
  ushort4* qo = (ushort4*)(fn + (size_t)row * 512) + lane * 2;
  qo[0] = o0; qo[1] = o1;
}

// ================= k_fused: 8-phase 256x256 tile + fused cube/echo =================
// LDS (shorts): buf0 @0, buf1 @32768 (each: Ah0|Bh0|Ah1|Bh1 x 8192), excT tile @65536 (8192)
#define BUFSZ 32768
#define EXL 65536

// stage one 128x64 half-tile (2 gload_lds/thread); src pre-offset to half row0 + kt col; ld=512
__device__ __forceinline__ void stage_half(const unsigned short* __restrict__ src,
                                           unsigned short* smem, int dsoff, int tid) {
  const int rowh = tid >> 3;
  const unsigned short* g = src + (size_t)rowh * 512 + (((tid & 7) ^ (rowh & 7)) << 3);
  __builtin_amdgcn_global_load_lds(
      (const __attribute__((address_space(1))) unsigned int*)g,
      (__attribute__((address_space(3))) unsigned int*)(smem + dsoff + tid * 8), 16, 0, 0);
  __builtin_amdgcn_global_load_lds(
      (const __attribute__((address_space(1))) unsigned int*)(g + 64 * 512),
      (__attribute__((address_space(3))) unsigned int*)(smem + dsoff + 4096 + tid * 8), 16, 0, 0);
}

// stage excT slice [32 cls][256 cols] -> EXL, swizzled
__device__ __forceinline__ void stage_exc(const unsigned short* __restrict__ excTg, int c0,
                                          unsigned short* smem, int tid) {
  const int row = tid >> 5, b = tid & 31;
  const int sb = ((b & 24) | ((b ^ (row & 7)) & 7)) << 3;
  const unsigned short* g = excTg + (size_t)row * 16384 + c0 + sb;
  __builtin_amdgcn_global_load_lds(
      (const __attribute__((address_space(1))) unsigned int*)g,
      (__attribute__((address_space(3))) unsigned int*)(smem + EXL + tid * 8), 16, 0, 0);
  __builtin_amdgcn_global_load_lds(
      (const __attribute__((address_space(1))) unsigned int*)(g + 16 * 16384),
      (__attribute__((address_space(3))) unsigned int*)(smem + EXL + 4096 + tid * 8), 16, 0, 0);
}

// one phase: C-quadrant (MH,NH), 12 ds_read_b128 + 16 MFMA
template<int MH, int NH>
__device__ __forceinline__ void mma_phase(const unsigned short* smem, int bufR,
                                          int wr, int wc, int r, int q, int rx,
                                          f32x4 acc[2][2][4][2]) {
  const unsigned short* A = smem + bufR + MH * 16384 + (wr * 64 + r) * 64;
  const unsigned short* B = smem + bufR + 8192 + NH * 16384 + (wc * 32 + r) * 64;
  const int s0 = (q ^ rx) << 3, s1 = ((4 + q) ^ rx) << 3;
  const s16x8 b00 = *(const s16x8*)(B + s0),        b01 = *(const s16x8*)(B + s1);
  const s16x8 b10 = *(const s16x8*)(B + 1024 + s0), b11 = *(const s16x8*)(B + 1024 + s1);
  #pragma unroll
  for (int fi = 0; fi < 4; ++fi) {
    const s16x8 a0 = *(const s16x8*)(A + fi * 1024 + s0);
    acc[MH][NH][fi][0] = MFMA16(a0, b00, acc[MH][NH][fi][0]);
    acc[MH][NH][fi][1] = MFMA16(a0, b10, acc[MH][NH][fi][1]);
    const s16x8 a1 = *(const s16x8*)(A + fi * 1024 + s1);
    acc[MH][NH][fi][0] = MFMA16(a1, b01, acc[MH][NH][fi][0]);
    acc[MH][NH][fi][1] = MFMA16(a1, b11, acc[MH][NH][fi][1]);
  }
}

__global__ __launch_bounds__(512, 2) void k_fused(const unsigned short* __restrict__ fnall,
                                                  const unsigned short* __restrict__ excT,
                                                  float* __restrict__ partial) {
  __shared__ __align__(16) unsigned short smem[73728];  // 144 KB
  const int tid = threadIdx.x, w = tid >> 6, lane = tid & 63;
  const int wr = w >> 2, wc = w & 3, r = lane & 15, q = lane >> 4, rx = r & 7;
  const int r0 = blockIdx.x * 256;     // 32 M-tiles
  const int nchunk = blockIdx.y;       // 16 chunks x 4 j-tiles of 256
  const unsigned short* Abase = fnall + (size_t)r0 * 512;
  const unsigned short* Ebase = fnall + (size_t)8192 * 512;
  unsigned short* aLb = smem + BUFSZ;  // echo scratch = buf1 (free at echo time)

  f32x4 acc[2][2][4][2];
  f32x4 eacc[2][2];
  #pragma unroll
  for (int a = 0; a < 2; ++a)
    #pragma unroll
    for (int b = 0; b < 2; ++b) eacc[a][b] = {0.f, 0.f, 0.f, 0.f};

  // prologue: kt=0's 4 half-tiles -> buf0 (queue order Ah0,Bh0,Ah1,Bh1)
  {
    const unsigned short* B0p = Ebase + (size_t)(nchunk * 4) * 256 * 512;
    stage_half(Abase, smem, 0, tid);
    stage_half(B0p, smem, 8192, tid);
    stage_half(Abase + 128 * 512, smem, 16384, tid);
    stage_half(B0p + 128 * 512, smem, 24576, tid);
  }

  for (int jt = 0; jt < 4; ++jt) {
    #pragma unroll
    for (int a = 0; a < 2; ++a)
      #pragma unroll
      for (int b = 0; b < 2; ++b)
        #pragma unroll
        for (int fi = 0; fi < 4; ++fi)
          #pragma unroll
          for (int fj = 0; fj < 2; ++fj) acc[a][b][fi][fj] = {0.f, 0.f, 0.f, 0.f};

    for (int tk = 0; tk < 8; ++tk) {
      const int kt = jt * 8 + tk;
      const int bufR = (kt & 1) * BUFSZ, bufW = bufR ^ BUFSZ;
      const int kn = (kt + 1) & 31;    // next K-tile (wraps; kt=31 re-stages harmlessly)
      const unsigned short* An = Abase + (kn & 7) * 64;
      const unsigned short* Bn = Ebase + (size_t)((nchunk * 4 + (kn >> 3)) * 256) * 512 + (kn & 7) * 64;
      // ---- phase 0: quadrant (0,0); stage Ah0(kn)
      PHASE_SYNC(4);
      stage_half(An, smem, bufW + 0, tid);
      if (tk == 7) stage_exc(excT, (nchunk * 4 + jt) * 256, smem, tid);
      SP1(); mma_phase<0, 0>(smem, bufR, wr, wc, r, q, rx, acc); SP0();
      // ---- phase 1: quadrant (1,0); stage Bh0(kn)
      PHASE_SYNC(4);
      stage_half(Bn, smem, bufW + 8192, tid);
      SP1(); mma_phase<1, 0>(smem, bufR, wr, wc, r, q, rx, acc); SP0();
      // ---- phase 2: quadrant (1,1); stage Ah1(kn)
      PHASE_SYNC(4);
      stage_half(An + 128 * 512, smem, bufW + 16384, tid);
      SP1(); mma_phase<1, 1>(smem, bufR, wr, wc, r, q, rx, acc); SP0();
      // ---- phase 3: quadrant (0,1); stage Bh1(kn); no vm wait
      PHASE_SYNC_NOVM();
      stage_half(Bn + 128 * 512, smem, bufW + 24576, tid);
      SP1(); mma_phase<0, 1>(smem, bufR, wr, wc, r, q, rx, acc); SP0();
    }

    // ---- echo: a = s^3 via aL (=buf1, free), MFMA vs excT-lds; 2 row-halves of 128
    const int c0 = (nchunk * 4 + jt) * 256;
    SCHED_FENCE(); WAIT_LGKM(); WAIT_VM(6); BAR(); SCHED_FENCE();  // excT landed; 3 halves of next kt in flight
    #pragma unroll
    for (int h = 0; h < 2; ++h) {
      // cube-write own quadrants of half h
      #pragma unroll
      for (int nh = 0; nh < 2; ++nh)
        #pragma unroll
        for (int fi = 0; fi < 4; ++fi)
          #pragma unroll
          for (int fj = 0; fj < 2; ++fj) {
            const int colc = nh * 128 + wc * 32 + fj * 16 + r;
            const int cb = colc >> 3, cl = colc & 7;
            #pragma unroll
            for (int t2 = 0; t2 < 4; ++t2) {
              const int row = wr * 64 + fi * 16 + q * 4 + t2;
              const float v = acc[h][nh][fi][fj][t2];
              aLb[row * 256 + ((((cb & 24) | ((cb ^ (row & 7)) & 7)) << 3) | cl)] = f2bf(v * v * v);
            }
          }
      SCHED_FENCE(); WAIT_LGKM(); BAR(); SCHED_FENCE();
      // echo MFMA: wave w owns rows w*16..+15 of this half; K=256, N=32
      {
        const int rE = w * 16 + r;
        const int re8 = rE & 7;
        #pragma unroll
        for (int kc = 0; kc < 8; ++kc) {
          const int kb = kc * 4 + q;
          const s16x8 af = *(const s16x8*)(aLb + rE * 256 + (((kb & 24) | ((kb ^ re8) & 7)) << 3));
          #pragma unroll
          for (int nj = 0; nj < 2; ++nj) {
            const s16x8 bfr = *(const s16x8*)(smem + EXL + (nj * 16 + r) * 256 +
                                              (((kb & 24) | ((kb ^ rx) & 7)) << 3));
            eacc[h][nj] = MFMA16(af, bfr, eacc[h][nj]);
          }
        }
      }
      SCHED_FENCE(); WAIT_LGKM(); BAR(); SCHED_FENCE();
    }
  }

  // write partial [nchunk][8192][32]
  #pragma unroll
  for (int h = 0; h < 2; ++h)
    #pragma unroll
    for (int nj = 0; nj < 2; ++nj) {
      const int rb = r0 + h * 128 + w * 16 + q * 4;
      const int cls = nj * 16 + r;
      #pragma unroll
      for (int t = 0; t < 4; ++t)
        partial[((size_t)nchunk * 8192 + rb + t) * 32 + cls] = eacc[h][nj][t];
    }
}

// ---------------- reduce 16 partials, /b, clip ----------------
__global__ void k_reduce(const float* __restrict__ partial, const float* __restrict__ bvec,
                         float* __restrict__ out) {
  const int idx = blockIdx.x * 256 + threadIdx.x;  // 229376 total
  const int row = idx / 28, c = idx - row * 28;
  float s = 0.f;
  #pragma unroll
  for (int nc = 0; nc < 16; ++nc) s += partial[((size_t)nc * 8192 + row) * 32 + c];
  out[idx] = fminf(fmaxf(s / bvec[c], 0.f), 1.f);
}

extern "C" void kernel_launch(void* const* d_in, const int* in_sizes, int n_in,
                              void* d_out, int out_size, void* d_ws, size_t ws_size,
                              hipStream_t stream) {
  const float* features    = (const float*)d_in[0];  // [8192,1024]
  const float* ex_features = (const float*)d_in[1];  // [16384,1024]
  const float* g_w         = (const float*)d_in[2];  // [512,1024]
  const float* g_b         = (const float*)d_in[3];  // [512]
  const float* ex_classes  = (const float*)d_in[4];  // [16384,28]
  float* out = (float*)d_out;
  char* ws = (char*)d_ws;

  unsigned short* featbf = (unsigned short*)(ws + 0);
  unsigned short* exbf   = (unsigned short*)(ws + 16777216);
  unsigned short* fnall  = (unsigned short*)(ws + 0);
  float* fall            = (float*)(ws + 50331648);
  float* partial         = (float*)(ws + 50331648);
  unsigned short* gwbf   = (unsigned short*)(ws + 100663296);
  unsigned short* excT   = (unsigned short*)(ws + 101711872);
  float* bvec            = (float*)(ws + 102760448);

  k_cast_bf16<<<2048, 256, 0, stream>>>(features, featbf, 8192 * 1024 / 4);
  k_cast_bf16<<<2048, 256, 0, stream>>>(ex_features, exbf, 16384 * 1024 / 4);
  k_cast_bf16<<<512, 256, 0, stream>>>(g_w, gwbf, 512 * 1024 / 4);
  k_excT<<<32, 256, 0, stream>>>(ex_classes, excT, bvec);
  k_proj<<<dim3(96, 4), 512, 0, stream>>>(featbf, exbf, gwbf, g_b, fall);
  k_norm<<<6144, 256, 0, stream>>>(fall, fnall);
  k_fused<<<dim3(32, 16), 512, 0, stream>>>(fnall, excT, partial);
  k_reduce<<<896, 256, 0, stream>>>(partial, bvec, out);
}